// Round 1
// baseline (585.369 us; speedup 1.0000x reference)
//
#include <hip/hip_runtime.h>

using bf16_t = __bf16;
using bf16x8 = __attribute__((ext_vector_type(8))) bf16_t;
using bf16x4 = __attribute__((ext_vector_type(4))) bf16_t;
using f32x4  = __attribute__((ext_vector_type(4))) float;

#define MFMA16(a, b, c) __builtin_amdgcn_mfma_f32_16x16x32_bf16((a), (b), (c), 0, 0, 0)

__device__ inline f32x4 zero4() {
    f32x4 z; z[0] = 0.f; z[1] = 0.f; z[2] = 0.f; z[3] = 0.f; return z;
}

// ---------------------------------------------------------------------------
// Kernel 1: RMSNorm + QKV projection.
// Block = 64 positions (one p-row segment), 256 threads (4 waves).
// Writes q_ws, k_ws as [pos][128] bf16; v transposed as vt_ws [p][f][key] bf16.
// ---------------------------------------------------------------------------
__global__ __launch_bounds__(256) void qkv_kernel(
    const float* __restrict__ x, const float* __restrict__ nscale,
    const float* __restrict__ wq, const float* __restrict__ wk,
    const float* __restrict__ wv, const float* __restrict__ bv,
    bf16_t* __restrict__ q_ws, bf16_t* __restrict__ k_ws,
    bf16_t* __restrict__ vt_ws)
{
    // aliased: phase1/2 use h[64][136]; epilogue reuses as vt[128][72]
    __shared__ __align__(16) bf16_t smem[128 * 72]; // 18432 B >= 64*136*2
    bf16_t* h  = smem;
    bf16_t* vt = smem;

    const int tid   = threadIdx.x;
    const int mbase = blockIdx.x * 64;

    // ---- Phase 1: RMSNorm -> h (bf16, row stride 136) ----
    {
        const int row = tid >> 2;   // 0..63
        const int qtr = tid & 3;    // 4 threads per row, 32 f each
        const float4* xr = reinterpret_cast<const float4*>(x + (size_t)(mbase + row) * 128) + qtr * 8;
        const float4* sc = reinterpret_cast<const float4*>(nscale) + qtr * 8;
        float4 xv[8];
        float ss = 0.f;
#pragma unroll
        for (int i = 0; i < 8; ++i) {
            xv[i] = xr[i];
            ss += xv[i].x * xv[i].x + xv[i].y * xv[i].y + xv[i].z * xv[i].z + xv[i].w * xv[i].w;
        }
        ss += __shfl_xor(ss, 1);
        ss += __shfl_xor(ss, 2);
        const float rs = rsqrtf(ss * (1.0f / 128.0f) + 1e-6f);
#pragma unroll
        for (int i = 0; i < 8; ++i) {
            const float4 s = sc[i];
            bf16x4 hv;
            hv[0] = (bf16_t)(xv[i].x * rs * s.x);
            hv[1] = (bf16_t)(xv[i].y * rs * s.y);
            hv[2] = (bf16_t)(xv[i].z * rs * s.z);
            hv[3] = (bf16_t)(xv[i].w * rs * s.w);
            *reinterpret_cast<bf16x4*>(h + row * 136 + qtr * 32 + i * 4) = hv;
        }
    }
    __syncthreads();

    const int lane = tid & 63;
    const int w    = tid >> 6;     // wave 0..3, owns 96 output cols
    const int lrow = lane & 15;
    const int lgrp = lane >> 4;

    // ---- A fragments: full 64x128 h tile, 16 x bf16x8 per lane ----
    bf16x8 afr[4][4];
#pragma unroll
    for (int mt = 0; mt < 4; ++mt)
#pragma unroll
        for (int ks = 0; ks < 4; ++ks)
            afr[mt][ks] = *reinterpret_cast<const bf16x8*>(
                h + (mt * 16 + lrow) * 136 + ks * 32 + lgrp * 8);
    __syncthreads();   // h is dead after this; smem may be reused as vt

    // ---- GEMM: acc[mt][nt] over 64 rows x 96 cols per wave ----
    f32x4 acc[4][6];
#pragma unroll
    for (int mt = 0; mt < 4; ++mt)
#pragma unroll
        for (int nt = 0; nt < 6; ++nt)
            acc[mt][nt] = zero4();

#pragma unroll
    for (int nt = 0; nt < 6; ++nt) {
        const int gcol = w * 96 + nt * 16;                    // 0..383, tile-uniform
        const float* wptr = (gcol < 128) ? wq : ((gcol < 256) ? wk : wv);
        const float* wrow = wptr + (size_t)((gcol & 127) + lrow) * 128 + lgrp * 8;
#pragma unroll
        for (int ks = 0; ks < 4; ++ks) {
            const float4 w0 = *reinterpret_cast<const float4*>(wrow + ks * 32);
            const float4 w1 = *reinterpret_cast<const float4*>(wrow + ks * 32 + 4);
            bf16x8 bfr;
            bfr[0] = (bf16_t)w0.x; bfr[1] = (bf16_t)w0.y;
            bfr[2] = (bf16_t)w0.z; bfr[3] = (bf16_t)w0.w;
            bfr[4] = (bf16_t)w1.x; bfr[5] = (bf16_t)w1.y;
            bfr[6] = (bf16_t)w1.z; bfr[7] = (bf16_t)w1.w;
#pragma unroll
            for (int mt = 0; mt < 4; ++mt)
                acc[mt][nt] = MFMA16(afr[mt][ks], bfr, acc[mt][nt]);
        }
    }

    // ---- Epilogue: q,k -> global bf16; v -> LDS transpose then global ----
    const int p  = mbase >> 9;
    const int kb = mbase & 511;
#pragma unroll
    for (int nt = 0; nt < 6; ++nt) {
        const int gcol = w * 96 + nt * 16 + lrow;
#pragma unroll
        for (int mt = 0; mt < 4; ++mt) {
#pragma unroll
            for (int r = 0; r < 4; ++r) {
                const int mloc = mt * 16 + lgrp * 4 + r;   // C layout: row=(lane>>4)*4+r
                const float val = acc[mt][nt][r];
                if (gcol < 128) {
                    q_ws[(size_t)(mbase + mloc) * 128 + gcol] = (bf16_t)val;
                } else if (gcol < 256) {
                    k_ws[(size_t)(mbase + mloc) * 128 + (gcol - 128)] = (bf16_t)val;
                } else {
                    const int f = gcol - 256;
                    vt[f * 72 + mloc] = (bf16_t)(val + bv[f]);
                }
            }
        }
    }
    __syncthreads();
    // coalesced copy vt[128][64] -> vt_ws[p][f][kb..kb+63]
#pragma unroll
    for (int it = 0; it < 4; ++it) {
        const int c  = it * 256 + tid;   // 1024 chunks of 8 bf16
        const int f  = c >> 3;
        const int ko = (c & 7) * 8;
        *reinterpret_cast<bf16x8*>(vt_ws + ((size_t)p * 128 + f) * 512 + kb + ko) =
            *reinterpret_cast<const bf16x8*>(vt + f * 72 + ko);
    }
}

// ---------------------------------------------------------------------------
// Kernel 2: per-row flash attention. Block = (p, 64-query tile), 4 waves.
// Wave handles 16 queries; online softmax; K staged in LDS; V frags from
// global vt_ws (contiguous in key); P bounced through per-wave LDS.
// ---------------------------------------------------------------------------
__global__ __launch_bounds__(256) void attn_kernel(
    const bf16_t* __restrict__ q_ws, const bf16_t* __restrict__ k_ws,
    const bf16_t* __restrict__ vt_ws, float* __restrict__ out)
{
    __shared__ __align__(16) bf16_t klds[64 * 136];
    __shared__ __align__(16) bf16_t plds[4][16 * 72];

    const int tid  = threadIdx.x;
    const int lane = tid & 63;
    const int w    = tid >> 6;
    const int lrow = lane & 15;
    const int lgrp = lane >> 4;

    const int p     = blockIdx.x >> 3;
    const int qt    = blockIdx.x & 7;
    const int qbase = qt * 64 + w * 16;

    // Q fragments held in registers for the whole kernel
    bf16x8 qfr[4];
    {
        const bf16_t* qp = q_ws + ((size_t)p * 512 + qbase + lrow) * 128 + lgrp * 8;
#pragma unroll
        for (int ks = 0; ks < 4; ++ks)
            qfr[ks] = *reinterpret_cast<const bf16x8*>(qp + ks * 32);
    }

    f32x4 oacc[8];
#pragma unroll
    for (int i = 0; i < 8; ++i) oacc[i] = zero4();
    float mrun[4], ssum[4];
#pragma unroll
    for (int r = 0; r < 4; ++r) { mrun[r] = -__builtin_inff(); ssum[r] = 0.f; }

    const float scale = 0.08838834764831845f; // 1/sqrt(128)
    bf16_t* pw = plds[w];

    for (int kt = 0; kt < 8; ++kt) {
        __syncthreads();   // protect klds (and prev-iter plds reads)
#pragma unroll
        for (int it = 0; it < 4; ++it) {
            const int c   = it * 256 + tid;
            const int row = c >> 4;
            const int off = (c & 15) * 8;
            *reinterpret_cast<bf16x8*>(klds + row * 136 + off) =
                *reinterpret_cast<const bf16x8*>(
                    k_ws + ((size_t)p * 512 + kt * 64 + row) * 128 + off);
        }
        __syncthreads();

        // ---- S = Q K^T (16 queries x 64 keys per wave) ----
        f32x4 sacc[4];
#pragma unroll
        for (int nt = 0; nt < 4; ++nt) sacc[nt] = zero4();
#pragma unroll
        for (int nt = 0; nt < 4; ++nt)
#pragma unroll
            for (int ks = 0; ks < 4; ++ks) {
                const bf16x8 kf = *reinterpret_cast<const bf16x8*>(
                    klds + (nt * 16 + lrow) * 136 + ks * 32 + lgrp * 8);
                sacc[nt] = MFMA16(qfr[ks], kf, sacc[nt]);
            }
#pragma unroll
        for (int nt = 0; nt < 4; ++nt)
#pragma unroll
            for (int r = 0; r < 4; ++r) sacc[nt][r] *= scale;

        // ---- online softmax (row = query = lgrp*4+r; keys across 16 lanes x 4 nt) ----
        float pout[4][4];
        float corr[4];
#pragma unroll
        for (int r = 0; r < 4; ++r) {
            float mx = fmaxf(fmaxf(sacc[0][r], sacc[1][r]), fmaxf(sacc[2][r], sacc[3][r]));
            mx = fmaxf(mx, __shfl_xor(mx, 1));
            mx = fmaxf(mx, __shfl_xor(mx, 2));
            mx = fmaxf(mx, __shfl_xor(mx, 4));
            mx = fmaxf(mx, __shfl_xor(mx, 8));
            const float mnew = fmaxf(mrun[r], mx);
            corr[r] = __expf(mrun[r] - mnew);   // first iter: exp(-inf)=0
            mrun[r] = mnew;
            float rsum = 0.f;
#pragma unroll
            for (int nt = 0; nt < 4; ++nt) {
                const float e = __expf(sacc[nt][r] - mnew);
                pout[nt][r] = e;
                rsum += e;
            }
            rsum += __shfl_xor(rsum, 1);
            rsum += __shfl_xor(rsum, 2);
            rsum += __shfl_xor(rsum, 4);
            rsum += __shfl_xor(rsum, 8);
            ssum[r] = ssum[r] * corr[r] + rsum;
        }
#pragma unroll
        for (int f8 = 0; f8 < 8; ++f8)
#pragma unroll
            for (int r = 0; r < 4; ++r) oacc[f8][r] *= corr[r];

        // ---- P (C layout) -> LDS -> A-fragment layout ----
#pragma unroll
        for (int nt = 0; nt < 4; ++nt)
#pragma unroll
            for (int r = 0; r < 4; ++r)
                pw[(lgrp * 4 + r) * 72 + nt * 16 + lrow] = (bf16_t)pout[nt][r];
        __syncthreads();

        // ---- O += P V ----
        const bf16_t* vp = vt_ws + (size_t)p * 128 * 512 + kt * 64 + lgrp * 8;
#pragma unroll
        for (int ks2 = 0; ks2 < 2; ++ks2) {
            const bf16x8 pf = *reinterpret_cast<const bf16x8*>(
                pw + lrow * 72 + ks2 * 32 + lgrp * 8);
#pragma unroll
            for (int f8 = 0; f8 < 8; ++f8) {
                const bf16x8 vf = *reinterpret_cast<const bf16x8*>(
                    vp + (size_t)(f8 * 16 + lrow) * 512 + ks2 * 32);
                oacc[f8] = MFMA16(pf, vf, oacc[f8]);
            }
        }
    }

    // ---- finalize: O / ssum, write fp32 ----
    float* op = out + ((size_t)p * 512 + qbase) * 128;
#pragma unroll
    for (int r = 0; r < 4; ++r) {
        const float inv = 1.0f / ssum[r];
#pragma unroll
        for (int f8 = 0; f8 < 8; ++f8)
            op[(lgrp * 4 + r) * 128 + f8 * 16 + lrow] = oacc[f8][r] * inv;
    }
}

// ---------------------------------------------------------------------------
extern "C" void kernel_launch(void* const* d_in, const int* in_sizes, int n_in,
                              void* d_out, int out_size, void* d_ws, size_t ws_size,
                              hipStream_t stream) {
    const float* x      = (const float*)d_in[0];
    const float* nscale = (const float*)d_in[1];
    const float* wq     = (const float*)d_in[2];
    const float* wk     = (const float*)d_in[3];
    const float* wv     = (const float*)d_in[4];
    const float* bv     = (const float*)d_in[5];
    float* out = (float*)d_out;

    // workspace: q (64 MiB) | k (64 MiB) | vT (64 MiB), all bf16
    char* ws = (char*)d_ws;
    bf16_t* q_ws  = (bf16_t*)ws;
    bf16_t* k_ws  = (bf16_t*)(ws + ((size_t)64 << 20));
    bf16_t* vt_ws = (bf16_t*)(ws + ((size_t)128 << 20));

    qkv_kernel<<<dim3(4096), dim3(256), 0, stream>>>(
        x, nscale, wq, wk, wv, bv, q_ws, k_ws, vt_ws);
    attn_kernel<<<dim3(4096), dim3(256), 0, stream>>>(
        q_ws, k_ws, vt_ws, out);
}